// Round 1
// baseline (43.762 us; speedup 1.0000x reference)
//
#include <hip/hip_runtime.h>

// NCC loss, streaming: full-row C=8, (I,J)-packed fp16, PREFETCH DISTANCE 6.
// I,J fp32 (32,1,512,512), 9x9 box, zero-pad, /81. R21 (42.3us): prefetch-1
// hid exactly one step of compute (~480cyc) off a ~2900cyc/step load-to-use
// latency at 1 wave/SIMD (grid==1024==#SIMDs, VALUBusy 16%). Per-step time
// T = max(C, L/D) -> need D ~ L/C ~ 6. R22: 6-slot load ring (24 float4 in
// flight, vmcnt(20) at each consume), chunk=18 keeps both si2%9 (data ring)
// and si2%6 (buffer ring) static. Issues are UNCONDITIONAL in every body so
// the waitcnt legalizer's static counts stay exact across the ch back-edge
// (steady state 24 outstanding at body entry/exit on both k<32 paths).
// +64 VGPR (~200 total), still 1-wave tier; occupancy stays grid-limited.
// DPP bound_ctrl edge zeros == image zero-padding (no masks); cross-term via
// d*swap(d); rings store rounded h2 once (add==evict bits -> telescoping).

constexpr int BATCH = 32;
constexpr int H = 512, W = 512;
constexpr int YB = 16;
constexpr int NBAND = H / YB;  // 32
constexpr float EPS81 = 81.0f * 81.0f * 1e-5f;  // ncc = R^2/(P*Q+EPS81)

using h2 = __attribute__((ext_vector_type(2))) _Float16;

__global__ void zero_accum(float* ws) { ws[0] = 0.0f; }

__device__ __forceinline__ h2 up1(h2 x) {  // lane i <- i-1 (wave_shr:1), edge=0
  return __builtin_bit_cast(
      h2, __builtin_amdgcn_update_dpp(0, __builtin_bit_cast(int, x), 0x138, 0xF,
                                      0xF, true));
}
__device__ __forceinline__ h2 dn1(h2 x) {  // lane i <- i+1 (wave_shl:1), edge=0
  return __builtin_bit_cast(
      h2, __builtin_amdgcn_update_dpp(0, __builtin_bit_cast(int, x), 0x130, 0xF,
                                      0xF, true));
}
// pack (I,J) -> h2 (RTZ) then AND-mask (wave-uniform y zero-pad)
__device__ __forceinline__ h2 pkm(float lo, float hi, unsigned m) {
  const unsigned u =
      __builtin_bit_cast(unsigned, __builtin_amdgcn_cvt_pkrtz(lo, hi)) & m;
  return __builtin_bit_cast(h2, u);
}
__device__ __forceinline__ h2 swp(h2 x) {  // swap halves (folds to op_sel)
  return __builtin_shufflevector(x, x, 1, 0);
}

// 9-tap centered window sums, 8 contiguous cols/lane (whole 512-col row).
__device__ __forceinline__ void tap8(const h2 u[8], h2 O[8]) {
  const h2 P0 = u[0], P1 = P0 + u[1], P2 = P1 + u[2], P3 = P2 + u[3],
           P4 = P3 + u[4], P5 = P4 + u[5], P6 = P5 + u[6], T = P6 + u[7];
  const h2 UP3 = up1(P3), UP4 = up1(P4), UP5 = up1(P5), UP6 = up1(P6), UT = up1(T);
  const h2 DP0 = dn1(P0), DP1 = dn1(P1), DP2 = dn1(P2), DP3 = dn1(P3);
  O[0] = (UT - UP3) + P4;
  O[1] = (UT - UP4) + P5;
  O[2] = (UT - UP5) + P6;
  O[3] = (UT - UP6) + T;
  O[4] = T + DP0;
  O[5] = (T - P0) + DP1;
  O[6] = (T - P1) + DP2;
  O[7] = (T - P2) + DP3;
}

__global__ __launch_bounds__(64, 1) void ncc_stream(const float* __restrict__ I,
                                                    const float* __restrict__ J,
                                                    float* __restrict__ accum) {
  const int lane = threadIdx.x;
  const int blk = blockIdx.x;
  const int band = blk & (NBAND - 1);
  const int b = blk >> 5;  // batch 0..31
  const int yb = band * YB;
  const int x0 = 8 * lane;
  const h2 zero2 = {_Float16(0.0f), _Float16(0.0f)};
  const h2 ninv81 = {_Float16(-1.0f / 81.0f), _Float16(-1.0f / 81.0f)};

  const float* __restrict__ Ib = I + (size_t)b * (H * W);
  const float* __restrict__ Jb = J + (size_t)b * (H * W);

  // mod-9 rings (packed I,J), all indices compile-time in the unrolled body
  h2 rg[9][8];   // raw ring: (I, J)
  h2 d9[9][8];   // dI/dJ ring: (dI, dJ)
  h2 V[8];       // running vertical sum of raw
  h2 vpq[8];     // (sum dI^2, sum dJ^2)
  h2 vr[8];      // (sum dI*dJ, same)
#pragma unroll
  for (int s = 0; s < 9; ++s)
#pragma unroll
    for (int c = 0; c < 8; ++c) { rg[s][c] = zero2; d9[s][c] = zero2; }
#pragma unroll
  for (int c = 0; c < 8; ++c) { V[c] = zero2; vpq[c] = zero2; vr[c] = zero2; }
  float acc = 0.f;

  // 6-slot prefetch ring (static slot index after unroll: si2 % 6, 18 % 6 == 0)
  float4 bI0[6], bI1[6], bJ0[6], bJ1[6];
#pragma unroll
  for (int j = 0; j < 6; ++j) {
    const int y0 = yb - 8 + j;
    const int yc0 = y0 < 0 ? 0 : (y0 > H - 1 ? H - 1 : y0);
    const int off0 = yc0 * W + x0;
    bI0[j] = *reinterpret_cast<const float4*>(Ib + off0);
    bI1[j] = *reinterpret_cast<const float4*>(Ib + off0 + 4);
    bJ0[j] = *reinterpret_cast<const float4*>(Jb + off0);
    bJ1[j] = *reinterpret_cast<const float4*>(Jb + off0 + 4);
  }

  // k=0..31: y = yb-8+k. k>=8: stage1 at m=y-4. k>=16: stage2 + output o=y-8.
#pragma unroll 1
  for (int ch = 0; ch < 2; ++ch) {
#pragma unroll
    for (int si2 = 0; si2 < 18; ++si2) {
      const int k = ch * 18 + si2;
      if (k < 32) {
        const int si = si2 % 9;        // data ring slot (static)
        const int t = (si + 5) % 9;    // center slot (static)
        const int sl = si2 % 6;        // prefetch ring slot (static)
        const int y = yb - 8 + k;
        const unsigned msk = ((y >= 0) & (y < H)) ? 0xFFFFFFFFu : 0u;

        // 1) consume slot sl (loads issued 6 steps ago; vmcnt leaves 20 in
        //    flight): pack (I,J), AND-mask y-pad
        h2 na[8];
        na[0] = pkm(bI0[sl].x, bJ0[sl].x, msk);
        na[1] = pkm(bI0[sl].y, bJ0[sl].y, msk);
        na[2] = pkm(bI0[sl].z, bJ0[sl].z, msk);
        na[3] = pkm(bI0[sl].w, bJ0[sl].w, msk);
        na[4] = pkm(bI1[sl].x, bJ1[sl].x, msk);
        na[5] = pkm(bI1[sl].y, bJ1[sl].y, msk);
        na[6] = pkm(bI1[sl].z, bJ1[sl].z, msk);
        na[7] = pkm(bI1[sl].w, bJ1[sl].w, msk);

        // 2) REISSUE slot sl for step k+6 (unconditional: keeps waitcnt
        //    bookkeeping exact; clamped row addr makes overshoot harmless)
        {
          const int yn = y + 6;
          const int ycn = yn < 0 ? 0 : (yn > H - 1 ? H - 1 : yn);
          const int offn = ycn * W + x0;
          bI0[sl] = *reinterpret_cast<const float4*>(Ib + offn);
          bI1[sl] = *reinterpret_cast<const float4*>(Ib + offn + 4);
          bJ0[sl] = *reinterpret_cast<const float4*>(Jb + offn);
          bJ1[sl] = *reinterpret_cast<const float4*>(Jb + offn + 4);
        }

        // 3) vertical running sum: evict slot si (row y-9), write new
#pragma unroll
        for (int c = 0; c < 8; ++c) {
          V[c] += na[c] - rg[si][c];
          rg[si][c] = na[c];
        }

        if (k >= 8) {
          const int m = y - 4;
          if ((m >= 0) & (m < H)) {  // wave-uniform
            h2 M[8];
            tap8(V, M);
#pragma unroll
            for (int c = 0; c < 8; ++c) {
              const h2 d = M[c] * ninv81 + rg[t][c];  // (dI, dJ)
              const h2 o = d9[t][c];
              vpq[c] += d * d - o * o;                // (dI^2, dJ^2)
              vr[c] += d * swp(d) - o * swp(o);       // (dI*dJ, dI*dJ)
              d9[t][c] = d;
            }
          } else {  // m outside image: dI=dJ=0, eviction-only
#pragma unroll
            for (int c = 0; c < 8; ++c) {
              const h2 o = d9[t][c];
              vpq[c] -= o * o;
              vr[c] -= o * swp(o);
              d9[t][c] = zero2;
            }
          }

          if (k >= 16) {
            h2 P[8], R[8];
            tap8(vpq, P);  // (81^2 varI, 81^2 varJ) pre-scale
            tap8(vr, R);   // (81^2 cov, same)
#pragma unroll
            for (int c = 0; c < 8; ++c) {
              const float Pl = (float)P[c][0], Qh = (float)P[c][1];
              const float Rl = (float)R[c][0];
              acc += (Rl * Rl) * __builtin_amdgcn_rcpf(fmaf(Pl, Qh, EPS81));
            }
          }
        }
      }
    }
  }

  // wave reduction, one atomic per wave
#pragma unroll
  for (int off = 32; off > 0; off >>= 1) acc += __shfl_down(acc, off, 64);
  if (lane == 0) atomicAdd(accum, acc);
}

__global__ void finalize(const float* __restrict__ ws, float* __restrict__ out) {
  out[0] = -ws[0] * (1.0f / (float)((size_t)BATCH * H * W));
}

extern "C" void kernel_launch(void* const* d_in, const int* in_sizes, int n_in,
                              void* d_out, int out_size, void* d_ws, size_t ws_size,
                              hipStream_t stream) {
  const float* I = (const float*)d_in[0];
  const float* J = (const float*)d_in[1];
  float* out = (float*)d_out;
  float* acc = (float*)d_ws;

  zero_accum<<<1, 1, 0, stream>>>(acc);
  ncc_stream<<<BATCH * NBAND, 64, 0, stream>>>(I, J, acc);
  finalize<<<1, 1, 0, stream>>>(acc, out);
}